// Round 2
// 206811.963 us; speedup vs baseline: 1.9061x; 1.9061x over previous
//
#include <hip/hip_runtime.h>
#include <cstdint>

#define TPB 256
#define GRID_WGS 256

// problem dims
#define NB    32
#define TIN   400
#define TOUT  500
#define NMEL  80
#define EDIM  512
#define ARNN  1024
#define PDIM  256
#define ADIM  128
#define NGATE 4096

#define KSA 7        // attention-LSTM K = 1792 = 7 x 256
#define KSD 10       // decoder-LSTM   K = 2560 = 10 x 256
#define NTASK_A 112  // 16 j-tiles x 7 k-chunks
#define NTASK   272  // + 16 j-tiles x 10 k-chunks

// double-region offsets (units: doubles)
#define PM_OFF   0          // pmT[b][a][t] [32][128][400]
#define WFC_OFF  1638400    // [128][62]
#define AH_OFF   1646336
#define AC_OFF   1679104
#define DH_OFF   1711872
#define DC_OFF   1744640
#define CTX_OFF  1777408
#define AW_OFF   1793792
#define AWC_OFF  1806592
#define EN_OFF   1819392
#define PQ_OFF   1832192
#define PRE0_OFF 1836288
#define PRE1_OFF 1844480
#define DBL_END  1852672
// float region (units: floats, base = (float*)(ws + DBL_END))
#define PAF_OFF  0          // A partials [7][32][4096]
#define PDF_OFF  917504     // D partials [10][32][4096]
#define F_END    2228224
// barrier region: 16 uints after float region (IDENTICAL layout to proven kernel)
#define WS_BYTES ((size_t)DBL_END*8 + (size_t)F_END*4 + 64)

#define MEL_OFF  0
#define GATE_OFF 1280000
#define AL_OFF   1296000

// ---------------- agent-coherent (sc1, coherence-point) access wrappers ----------------
// All cross-WG mutable data goes through these. Relaxed agent-scope atomics lower to
// global_load/store ... sc1 (performed at the agent coherence point, which is coherent
// across XCDs) with NO cache-maintenance instructions. Read-only data (weights, memory,
// pmT, wfc, dec) keeps normal cached accesses and now stays L2-resident across steps.
__device__ __forceinline__ double ld_d(const double* p){
  return __hip_atomic_load(p, __ATOMIC_RELAXED, __HIP_MEMORY_SCOPE_AGENT);
}
__device__ __forceinline__ void st_d(double* p, double v){
  __hip_atomic_store(p, v, __ATOMIC_RELAXED, __HIP_MEMORY_SCOPE_AGENT);
}
__device__ __forceinline__ float ld_f(const float* p){
  return __hip_atomic_load(p, __ATOMIC_RELAXED, __HIP_MEMORY_SCOPE_AGENT);
}
__device__ __forceinline__ void st_f2(float* p, float a, float b){
  union { float f[2]; unsigned long long u; } x; x.f[0] = a; x.f[1] = b;
  __hip_atomic_store(reinterpret_cast<unsigned long long*>(p), x.u,
                     __ATOMIC_RELAXED, __HIP_MEMORY_SCOPE_AGENT);
}

// ---------------- fence-free monotone grid barrier ----------------
// Barrier #g (g starts at 1) completes when the monotone counter reaches g*GRID_WGS.
// No counter reset -> no cross-address ordering requirement -> ALL atomics relaxed ->
// no buffer_wbl2/buffer_inv anywhere. Ordering argument:
//  (a) __syncthreads() drains vmcnt(0) per wave, so every sc1 data store has reached
//      the coherence point before tid0's arrival RMW is issued (explicit waitcnt keeps
//      tid0's own stores ordered too);
//  (b) RMWs to the single counter serialize at the coherence point, so the 256th
//      arriver observes the full count; gen is bumped after, pollers wait for gen>=g;
//  (c) consumers' sc1 data loads are issued after the poll succeeds, and fetch from
//      the coherence point, so they see all pre-barrier data.
// Total arrivals: (1 + 501*4) * 256 = 513280 << 2^32.
__device__ __forceinline__ void gridbar(unsigned* cnt, unsigned* gen, int tid, unsigned g){
  __syncthreads();
  if (tid == 0){
    asm volatile("s_waitcnt vmcnt(0) lgkmcnt(0)" ::: "memory");
    unsigned old = __hip_atomic_fetch_add(cnt, 1u, __ATOMIC_RELAXED, __HIP_MEMORY_SCOPE_AGENT);
    if (old == g*(unsigned)GRID_WGS - 1u){
      __hip_atomic_fetch_add(gen, 1u, __ATOMIC_RELAXED, __HIP_MEMORY_SCOPE_AGENT);
    } else {
      while (__hip_atomic_load(gen, __ATOMIC_RELAXED, __HIP_MEMORY_SCOPE_AGENT) < g){
        __builtin_amdgcn_s_sleep(2);
      }
    }
  }
  __syncthreads();
}

// ---------------- threefry2x32 core (bit-exact JAX) ----------------
__device__ __forceinline__ uint32_t rotl32(uint32_t v, int r){ return (v<<r)|(v>>(32-r)); }

__device__ __forceinline__ void tf_block(uint32_t k0, uint32_t k1, uint32_t x0, uint32_t x1,
                                         uint32_t& y0, uint32_t& y1){
  uint32_t k2 = k0 ^ k1 ^ 0x1BD11BDAu;
  x0 += k0; x1 += k1;
#define TF4(r0,r1,r2,r3,ka,kb,inc) \
  x0 += x1; x1 = rotl32(x1,r0); x1 ^= x0; \
  x0 += x1; x1 = rotl32(x1,r1); x1 ^= x0; \
  x0 += x1; x1 = rotl32(x1,r2); x1 ^= x0; \
  x0 += x1; x1 = rotl32(x1,r3); x1 ^= x0; \
  x0 += (ka); x1 += (kb) + (inc);
  TF4(13,15,26,6,  k1,k2,1u)
  TF4(17,29,16,24, k2,k0,2u)
  TF4(13,15,26,6,  k0,k1,3u)
  TF4(17,29,16,24, k1,k2,4u)
  TF4(13,15,26,6,  k2,k0,5u)
#undef TF4
  y0 = x0; y1 = x1;
}

// ---- PARTITIONABLE threefry (jax_threefry_partitionable=True, modern JAX default) ----
__device__ __forceinline__ bool tf_keep_part(uint32_t k0, uint32_t k1, uint32_t i){
  uint32_t y0, y1;
  tf_block(k0, k1, 0u, i, y0, y1);
  return (((y0 ^ y1) >> 31) == 0u);
}

// ---------------- precompute kernels (fp64) ----------------
__global__ __launch_bounds__(TPB) void pm_kernel(
    const float* __restrict__ memory, const float* __restrict__ Wm, double* __restrict__ pmT)
{
  const int bt = blockIdx.x;           // b*400 + t
  const int b = bt / TIN, t2 = bt - b*TIN;
  const int tid = threadIdx.x;
  __shared__ double sm[EDIM];
  __shared__ double sp[TPB];
  for (int i = tid; i < EDIM; i += TPB) sm[i] = (double)memory[(size_t)bt*EDIM + i];
  __syncthreads();
  const int a = tid & 127, hf = tid >> 7;
  const float* w = Wm + (size_t)a*EDIM + hf*256;
  const double* x = sm + hf*256;
  double s = 0.0;
  for (int e = 0; e < 256; ++e) s += (double)w[e]*x[e];
  sp[tid] = s;
  __syncthreads();
  if (tid < ADIM) pmT[((size_t)b*ADIM + tid)*TIN + t2] = sp[tid] + sp[tid+128];
}

__global__ __launch_bounds__(TPB) void wfc_kernel(
    const float* __restrict__ Wd, const float* __restrict__ Wc, double* __restrict__ wfc)
{
  for (int o = threadIdx.x; o < ADIM*62; o += TPB){
    int a = o / 62, ck = o - a*62;
    double s = 0.0;
    for (int f = 0; f < 32; ++f) s += (double)Wd[a*32+f]*(double)Wc[f*62 + ck];
    wfc[o] = s;
  }
}

__global__ void bar_init_kernel(unsigned* bar){ bar[threadIdx.x] = 0u; }
__global__ void sentinel_kernel(float* out, float val){ out[0] = val; }

// ---------------- main persistent kernel ----------------
struct DecParams {
  const float *memory, *dec;
  const float *Wpre1, *Wpre2;
  const float *WihA,*WhhA,*bihA,*bhhA;
  const float *Wq,*v;
  const float *WihD,*WhhD,*bihD,*bhhD;
  const float *Wp,*bp,*Wg,*bg;
  const unsigned char* mask;
  double* ws;
  float* out;
};

__device__ __forceinline__ double sigd(double x){ return 1.0/(1.0+exp(-x)); }

__global__ __launch_bounds__(TPB, 1) void decoder_main(DecParams P)
{
  const int wg = blockIdx.x, tid = threadIdx.x;
  const int nwg = GRID_WGS;
  __shared__ __align__(16) double sb[4096];   // 32 KB

  double* ws  = P.ws;
  double* pmT = ws + PM_OFF;   double* wfc = ws + WFC_OFF;
  double* ah  = ws + AH_OFF;   double* ac  = ws + AC_OFF;
  double* dh  = ws + DH_OFF;   double* dc  = ws + DC_OFF;
  double* ctx = ws + CTX_OFF;  double* aw  = ws + AW_OFF;  double* awc = ws + AWC_OFF;
  double* en  = ws + EN_OFF;   double* pq  = ws + PQ_OFF;
  float*  pAf = (float*)(ws + DBL_END);
  float*  pDf = pAf + PDF_OFF;
  unsigned* bar = (unsigned*)(pAf + F_END);   // bar[0]=count (monotone), bar[1]=gen
  unsigned g = 0;

  // zero recurrent state + pre buffers (AH..DBL_END contiguous doubles) via sc1 stores
  for (int i = wg*TPB + tid; i < DBL_END - AH_OFF; i += nwg*TPB) st_d(ah + i, 0.0);
  gridbar(bar, bar+1, tid, ++g);

  #pragma unroll 1
  for (int t = 0; t <= TOUT; ++t){
    const double* pre_cur = ws + ((t & 1) ? PRE1_OFF : PRE0_OFF);

    // ---- PH1: fp64 gate-GEMM partials (A for step t, D for step t-1) ----
    for (int task = wg; task < NTASK; task += nwg){
      const bool isA = task < NTASK_A;
      if (isA ? (t < TOUT) : (t > 0)){
        int jt, ks;
        if (isA){ jt = task / KSA; ks = task - jt*KSA; }
        else    { int r = task - NTASK_A; jt = r / KSD; ks = r - jt*KSD; }
        const int kbase = ks*256;
        const int jg = tid & 63, bg = tid >> 6;
        const int j0 = jt*256 + jg*4;
        const float* wbase; int rowlen, koff;
        if (isA){
          if (kbase < 768){ wbase = P.WihA; rowlen = 768;  koff = kbase; }
          else            { wbase = P.WhhA; rowlen = 1024; koff = kbase-768; }
        } else {
          if (kbase < 1536){ wbase = P.WihD; rowlen = 1536; koff = kbase; }
          else             { wbase = P.WhhD; rowlen = 1024; koff = kbase-1536; }
        }
        const float* wr0 = wbase + (size_t)(j0+0)*rowlen + koff;
        const float* wr1 = wbase + (size_t)(j0+1)*rowlen + koff;
        const float* wr2 = wbase + (size_t)(j0+2)*rowlen + koff;
        const float* wr3 = wbase + (size_t)(j0+3)*rowlen + koff;
        double acc[32];
        #pragma unroll
        for (int i = 0; i < 32; ++i) acc[i] = 0.0;

        #pragma unroll 1
        for (int half = 0; half < 2; ++half){
          const int kb2 = kbase + half*128;
          if (isA){
            for (int i = tid; i < NB*128; i += TPB){
              const int b = i >> 7, kg = kb2 + (i & 127);
              double xv;
              if (kg < 256)       xv = ld_d(pre_cur + (b<<8) + kg);
              else if (kg < 768)  xv = ld_d(ctx + b*EDIM + (kg-256));
              else                xv = ld_d(ah + b*ARNN + (kg-768));
              sb[i] = xv;
            }
          } else {
            for (int i = tid; i < NB*128; i += TPB){
              const int b = i >> 7, kg = kb2 + (i & 127);
              double xv;
              if (kg < 1024)      xv = ld_d(ah + b*ARNN + kg);
              else if (kg < 1536) xv = ld_d(ctx + b*EDIM + (kg-1024));
              else                xv = ld_d(dh + b*ARNN + (kg-1536));
              sb[i] = xv;
            }
          }
          __syncthreads();
          const int kadd = half*128;
          #pragma unroll 1
          for (int kk = 0; kk < 128; kk += 4){
            const float4 f0 = *(const float4*)(wr0 + kadd + kk);
            const float4 f1 = *(const float4*)(wr1 + kadd + kk);
            const float4 f2 = *(const float4*)(wr2 + kadd + kk);
            const float4 f3 = *(const float4*)(wr3 + kadd + kk);
            const double w00=f0.x,w01=f0.y,w02=f0.z,w03=f0.w;
            const double w10=f1.x,w11=f1.y,w12=f1.z,w13=f1.w;
            const double w20=f2.x,w21=f2.y,w22=f2.z,w23=f2.w;
            const double w30=f3.x,w31=f3.y,w32=f3.z,w33=f3.w;
            #pragma unroll
            for (int bi = 0; bi < 8; ++bi){
              const double* xp = sb + (((bg<<3)+bi)<<7) + kk;
              const double x0=xp[0], x1=xp[1], x2=xp[2], x3=xp[3];
              acc[bi*4+0] += w00*x0 + w01*x1 + w02*x2 + w03*x3;
              acc[bi*4+1] += w10*x0 + w11*x1 + w12*x2 + w13*x3;
              acc[bi*4+2] += w20*x0 + w21*x1 + w22*x2 + w23*x3;
              acc[bi*4+3] += w30*x0 + w31*x1 + w32*x2 + w33*x3;
            }
          }
          __syncthreads();
        }

        float* pbase = (isA ? pAf : pDf) + ((size_t)ks*NB)*NGATE;
        #pragma unroll
        for (int bi = 0; bi < 8; ++bi){
          const int b = (bg<<3) + bi;
          float* pp = pbase + (size_t)b*NGATE + j0;
          st_f2(pp,   (float)acc[bi*4+0], (float)acc[bi*4+1]);
          st_f2(pp+2, (float)acc[bi*4+2], (float)acc[bi*4+3]);
        }
      }
    }
    gridbar(bar, bar+1, tid, ++g);

    // ---- PH1b: LSTM reduce + activations (+ pq = Wq @ ah), fp64 ----
    if (wg < NB){
      if (t < TOUT){
        const int b = wg;
        for (int h = tid; h < ARNN; h += TPB){
          double g0 = (double)P.bihA[h]      + (double)P.bhhA[h];
          double g1 = (double)P.bihA[1024+h] + (double)P.bhhA[1024+h];
          double g2 = (double)P.bihA[2048+h] + (double)P.bhhA[2048+h];
          double g3 = (double)P.bihA[3072+h] + (double)P.bhhA[3072+h];
          for (int p2 = 0; p2 < KSA; ++p2){
            const float* pp = pAf + ((size_t)p2*NB + b)*NGATE;
            g0 += (double)ld_f(pp + h);        g1 += (double)ld_f(pp + 1024 + h);
            g2 += (double)ld_f(pp + 2048 + h); g3 += (double)ld_f(pp + 3072 + h);
          }
          const double cp = ac[b*ARNN + h];
          const double cn = sigd(g1)*cp + sigd(g0)*tanh(g2);
          const double hn = sigd(g3)*tanh(cn);
          ac[b*ARNN+h] = cn;             // private to this WG: normal cached access
          st_d(ah + b*ARNN + h, hn);     // shared: sc1
          sb[h] = hn;
        }
        __syncthreads();
        {
          const int a2 = tid >> 1, hf = tid & 1;
          const float* wq = P.Wq + (size_t)a2*ARNN + hf*512;
          const double* xh = sb + hf*512;
          double s = 0.0;
          for (int h2 = 0; h2 < 512; ++h2) s += (double)wq[h2]*xh[h2];
          sb[1024 + tid] = s;
        }
        __syncthreads();
        if (tid < ADIM) st_d(pq + b*ADIM + tid, sb[1024 + 2*tid] + sb[1024 + 2*tid + 1]);
      }
    } else if (wg < 2*NB){
      if (t > 0){
        const int b = wg - NB;
        for (int h = tid; h < ARNN; h += TPB){
          double g0 = (double)P.bihD[h]      + (double)P.bhhD[h];
          double g1 = (double)P.bihD[1024+h] + (double)P.bhhD[1024+h];
          double g2 = (double)P.bihD[2048+h] + (double)P.bhhD[2048+h];
          double g3 = (double)P.bihD[3072+h] + (double)P.bhhD[3072+h];
          for (int p2 = 0; p2 < KSD; ++p2){
            const float* pp = pDf + ((size_t)p2*NB + b)*NGATE;
            g0 += (double)ld_f(pp + h);        g1 += (double)ld_f(pp + 1024 + h);
            g2 += (double)ld_f(pp + 2048 + h); g3 += (double)ld_f(pp + 3072 + h);
          }
          const double cp = dc[b*ARNN + h];
          const double cn = sigd(g1)*cp + sigd(g0)*tanh(g2);
          const double hn = sigd(g3)*tanh(cn);
          dc[b*ARNN+h] = cn;             // private: normal
          st_d(dh + b*ARNN + h, hn);     // shared: sc1
        }
      }
    }
    gridbar(bar, bar+1, tid, ++g);

    // ---- PH2: attention energies (t) + mel/gate (t-1), fp64 ----
    if (wg < 224){
      if (t < TOUT){
        const int b = wg / 7, tt = wg - b*7;
        const int tbase = tt*64;
        if (tid < ADIM) sb[tid] = ld_d(pq + b*ADIM + tid);
        for (int i = tid; i < 94; i += TPB){
          int tg = tbase - 15 + i;
          sb[128 + i] = (tg >= 0 && tg < TIN) ? ld_d(aw + b*TIN + tg) : 0.0;
        }
        for (int i = tid; i < 94; i += TPB){
          int tg = tbase - 15 + i;
          sb[222 + i] = (tg >= 0 && tg < TIN) ? ld_d(awc + b*TIN + tg) : 0.0;
        }
        __syncthreads();
        const int wv = tid >> 6, lane = tid & 63;
        const int tg = tbase + lane;
        double esum = 0.0;
        if (tg < TIN){
          double w0r[31], w1r[31];
          #pragma unroll
          for (int k = 0; k < 31; ++k){ w0r[k] = sb[128 + lane + k]; w1r[k] = sb[222 + lane + k]; }
          const double* pmrow = pmT + (size_t)b*ADIM*TIN + tg;
          for (int a2 = wv*32; a2 < wv*32 + 32; ++a2){
            const double* wf = wfc + a2*62;
            double cv = 0.0;
            #pragma unroll
            for (int k = 0; k < 31; ++k) cv += wf[k]*w0r[k];
            #pragma unroll
            for (int k = 0; k < 31; ++k) cv += wf[31+k]*w1r[k];
            const double e = sb[a2] + cv + pmrow[(size_t)a2*TIN];
            esum += (double)P.v[a2]*tanh(e);
          }
        }
        sb[640 + wv*64 + lane] = esum;
        __syncthreads();
        if (tid < 64){
          const int tg2 = tbase + tid;
          if (tg2 < TIN){
            double e = sb[640+tid] + sb[704+tid] + sb[768+tid] + sb[832+tid];
            if (P.mask[b*TIN + tg2]) e = -1e9;
            st_d(en + b*TIN + tg2, e);
          }
        }
      }
    } else if (wg < 256){
      if (t > 0){
        const int b = wg - 224, ts = t-1;
        for (int i = tid; i < 1536; i += TPB)
          sb[i] = (i < 1024) ? ld_d(dh + b*ARNN + i) : ld_d(ctx + b*EDIM + (i-1024));
        __syncthreads();
        const int o = tid >> 1, hf = tid & 1;
        double s = 0.0;
        if (o <= 80){
          const float* wr = ((o < 80) ? (P.Wp + (size_t)o*1536) : P.Wg) + hf*768;
          const double* xr = sb + hf*768;
          for (int m2 = 0; m2 < 768; ++m2) s += (double)wr[m2]*xr[m2];
        }
        sb[1600 + tid] = s;
        __syncthreads();
        if (tid <= 80){
          double val = sb[1600 + 2*tid] + sb[1600 + 2*tid + 1];
          if (tid < 80) P.out[MEL_OFF + ((size_t)b*NMEL + tid)*TOUT + ts] = (float)(val + (double)P.bp[tid]);
          else          P.out[GATE_OFF + (size_t)b*TOUT + ts] = (float)(val + (double)P.bg[0]);
        }
      }
    }
    gridbar(bar, bar+1, tid, ++g);

    // ---- PH3: softmax + context (WGs 0..31) | prenet t+1 (WGs 32..63), fp64 ----
    if (wg < NB){
      if (t < TOUT){
        const int b = wg;
        double m = -1.0e300;
        for (int i = tid; i < TIN; i += TPB){
          double e = ld_d(en + b*TIN + i);
          sb[512 + i] = e;                    // stash: single sc1 pass over en
          m = fmax(m, e);
        }
        sb[tid] = m; __syncthreads();
        for (int s2 = TPB/2; s2 > 0; s2 >>= 1){
          if (tid < s2) sb[tid] = fmax(sb[tid], sb[tid+s2]);
          __syncthreads();
        }
        const double mx = sb[0];
        __syncthreads();
        double ssum = 0.0;
        for (int i = tid; i < TIN; i += TPB){
          double u = exp(sb[512+i] - mx);
          sb[512 + i] = u; ssum += u;
        }
        sb[tid] = ssum; __syncthreads();
        for (int s2 = TPB/2; s2 > 0; s2 >>= 1){
          if (tid < s2) sb[tid] += sb[tid+s2];
          __syncthreads();
        }
        const double tot = sb[0];
        __syncthreads();
        for (int i = tid; i < TIN; i += TPB){
          double a2 = sb[512+i] / tot;
          sb[512+i] = a2;
          st_d(aw + b*TIN + i, a2);
          st_d(awc + b*TIN + i, ld_d(awc + b*TIN + i) + a2);
          P.out[AL_OFF + ((size_t)b*TOUT + t)*TIN + i] = (float)a2;
        }
        __syncthreads();
        for (int e2 = tid; e2 < EDIM; e2 += TPB){
          const float* mrow = P.memory + (size_t)b*TIN*EDIM + e2;
          double s = 0.0;
          for (int t2 = 0; t2 < TIN; ++t2) s += sb[512+t2]*(double)mrow[(size_t)t2*EDIM];
          st_d(ctx + b*EDIM + e2, s);
        }
      }
    } else if (wg < 2*NB){
      if (t < TOUT-1){
        const int b = wg - NB, t1 = t + 1;
        double* pre_next = ws + ((t1 & 1) ? PRE1_OFF : PRE0_OFF);
        for (int m = tid; m < NMEL; m += TPB)
          sb[m] = (double)P.dec[((size_t)b*NMEL + m)*TOUT + (t1-1)];
        __syncthreads();
        // PARTITIONABLE split of key(42)=(0,42): dk_i = full output of block(0, i)
        uint32_t d1k0, d1k1, d2k0, d2k1;
        tf_block(0u, 42u, 0u, 0u, d1k0, d1k1);   // dk1 = (y0, y1) @ counter 0
        tf_block(0u, 42u, 0u, 1u, d2k0, d2k1);   // dk2 = (y0, y1) @ counter 1
        const uint32_t flat = ((uint32_t)(t1*NB + b))*PDIM + tid;
        {
          const float* w = P.Wpre1 + tid*NMEL;
          double s = 0.0;
          for (int m = 0; m < NMEL; ++m) s += sb[m]*(double)w[m];
          double hv = tf_keep_part(d1k0, d1k1, flat) ? s*2.0 : 0.0;
          sb[128 + tid] = fmax(hv, 0.0);
        }
        __syncthreads();
        {
          const float* w = P.Wpre2 + tid*PDIM;
          double s = 0.0;
          for (int m = 0; m < PDIM; ++m) s += sb[128+m]*(double)w[m];
          double pv = tf_keep_part(d2k0, d2k1, flat) ? s*2.0 : 0.0;
          st_d(pre_next + (b<<8) + tid, fmax(pv, 0.0));
        }
      }
    }
    gridbar(bar, bar+1, tid, ++g);
  }
}

extern "C" void kernel_launch(void* const* d_in, const int* in_sizes, int n_in,
                              void* d_out, int out_size, void* d_ws, size_t ws_size,
                              hipStream_t stream)
{
  const float* memory = (const float*)d_in[0];
  const float* dec    = (const float*)d_in[1];
  const unsigned char* mask = (const unsigned char*)d_in[2];
  const float* W_pre1 = (const float*)d_in[3];
  const float* W_pre2 = (const float*)d_in[4];
  const float* WihA   = (const float*)d_in[5];
  const float* WhhA   = (const float*)d_in[6];
  const float* bihA   = (const float*)d_in[7];
  const float* bhhA   = (const float*)d_in[8];
  const float* Wq     = (const float*)d_in[9];
  const float* Wm     = (const float*)d_in[10];
  const float* v      = (const float*)d_in[11];
  const float* Wc     = (const float*)d_in[12];
  const float* Wd     = (const float*)d_in[13];
  const float* WihD   = (const float*)d_in[14];
  const float* WhhD   = (const float*)d_in[15];
  const float* bihD   = (const float*)d_in[16];
  const float* bhhD   = (const float*)d_in[17];
  const float* Wp     = (const float*)d_in[18];
  const float* bp     = (const float*)d_in[19];
  const float* Wg     = (const float*)d_in[20];
  const float* bg     = (const float*)d_in[21];

  double* ws = (double*)d_ws;
  float* out = (float*)d_out;

  if (ws_size < WS_BYTES){
    sentinel_kernel<<<1, 1, 0, stream>>>(out, 12345.0f);   // diagnostic: ws too small
    return;
  }

  unsigned* bar = (unsigned*)((float*)(ws + DBL_END) + F_END);
  bar_init_kernel<<<1, 16, 0, stream>>>(bar);
  pm_kernel<<<NB*TIN, TPB, 0, stream>>>(memory, Wm, ws + PM_OFF);
  wfc_kernel<<<1, TPB, 0, stream>>>(Wd, Wc, ws + WFC_OFF);

  DecParams P;
  P.memory = memory; P.dec = dec;
  P.Wpre1 = W_pre1; P.Wpre2 = W_pre2;
  P.WihA = WihA; P.WhhA = WhhA; P.bihA = bihA; P.bhhA = bhhA;
  P.Wq = Wq; P.v = v;
  P.WihD = WihD; P.WhhD = WhhD; P.bihD = bihD; P.bhhD = bhhD;
  P.Wp = Wp; P.bp = bp; P.Wg = Wg; P.bg = bg;
  P.mask = mask; P.ws = ws; P.out = out;

  decoder_main<<<GRID_WGS, TPB, 0, stream>>>(P);
}

// Round 3
// 193844.080 us; speedup vs baseline: 2.0336x; 1.0669x over previous
//
#include <hip/hip_runtime.h>
#include <cstdint>

#define TPB 256
#define GRID_WGS 256

// problem dims
#define NB    32
#define TIN   400
#define TOUT  500
#define NMEL  80
#define EDIM  512
#define ARNN  1024
#define PDIM  256
#define ADIM  128
#define NGATE 4096

#define KSA 7        // attention-LSTM K = 1792 = 7 x 256
#define KSD 10       // decoder-LSTM   K = 2560 = 10 x 256
#define NTASK_A 112  // 16 j-tiles x 7 k-chunks
#define NTASK   272  // + 16 j-tiles x 10 k-chunks

// double-region offsets (units: doubles)
#define PM_OFF   0          // pmT[b][a][t] [32][128][400]
#define WFC_OFF  1638400    // [128][62]
#define AH_OFF   1646336
#define AC_OFF   1679104
#define DH_OFF   1711872
#define DC_OFF   1744640
#define CTX_OFF  1777408
#define AW_OFF   1793792
#define AWC_OFF  1806592
#define EN_OFF   1819392
#define PQ_OFF   1832192
#define PRE0_OFF 1836288
#define PRE1_OFF 1844480
#define DBL_END  1852672
// float region (units: floats, base = (float*)(ws + DBL_END))
#define PAF_OFF  0          // A partials [7][32][4096]
#define PDF_OFF  917504     // D partials [10][32][4096]
#define F_END    2228224
// barrier region after float region: flags[256] (4B each) + gen at its own line
#define BAR_UINTS 320       // 1280 B: flags[0..255], gen at [256] (byte 1024, own 128B line)
#define GEN_IDX   256
#define WS_BYTES ((size_t)DBL_END*8 + (size_t)F_END*4 + (size_t)BAR_UINTS*4)

#define MEL_OFF  0
#define GATE_OFF 1280000
#define AL_OFF   1296000

// ---------------- agent-coherent (sc1, coherence-point) access wrappers ----------------
// All cross-WG mutable data goes through these. Relaxed agent-scope atomics lower to
// global_load/store ... sc1 (performed at the agent coherence point, coherent across
// XCDs) with NO cache-maintenance instructions. Read-only data (weights, memory, pmT,
// wfc, dec) keeps normal cached accesses and stays L2-resident across steps.
__device__ __forceinline__ double ld_d(const double* p){
  return __hip_atomic_load(p, __ATOMIC_RELAXED, __HIP_MEMORY_SCOPE_AGENT);
}
__device__ __forceinline__ void st_d(double* p, double v){
  __hip_atomic_store(p, v, __ATOMIC_RELAXED, __HIP_MEMORY_SCOPE_AGENT);
}
__device__ __forceinline__ float ld_f(const float* p){
  return __hip_atomic_load(p, __ATOMIC_RELAXED, __HIP_MEMORY_SCOPE_AGENT);
}
__device__ __forceinline__ void st_f2(float* p, float a, float b){
  union { float f[2]; unsigned long long u; } x; x.f[0] = a; x.f[1] = b;
  __hip_atomic_store(reinterpret_cast<unsigned long long*>(p), x.u,
                     __ATOMIC_RELAXED, __HIP_MEMORY_SCOPE_AGENT);
}

// ---------------- flag-array grid barrier (no RMW serialization, all relaxed) ----------
// Arrival: each WG's tid0 stores generation g to its OWN flag word -> 256 independent
// sc1 stores, fully parallel at the coherence point (the round-2 profile showed the
// single-address fetch_add arrival chain serializing at ~80us/barrier; plain stores to
// distinct addresses don't serialize). WG0's 256 threads poll the 256 flags in
// parallel (reads), then WG0 publishes gen=g; other WGs poll gen (same-line reads,
// broadcast-served, proven cheap in rounds 0/2). Monotone generations, no resets, no
// cross-address ordering requirement -> all atomics relaxed -> zero cache maintenance.
// Ordering: __syncthreads() drains vmcnt(0) per wave before s_barrier, so all sc1 data
// stores have reached the coherence point before tid0's flag store issues (explicit
// waitcnt orders tid0's own stores).
__device__ __forceinline__ void gridbar(unsigned* flags, unsigned* gen, int wg, int tid, unsigned g){
  __syncthreads();
  if (tid == 0){
    asm volatile("s_waitcnt vmcnt(0) lgkmcnt(0)" ::: "memory");
    __hip_atomic_store(flags + wg, g, __ATOMIC_RELAXED, __HIP_MEMORY_SCOPE_AGENT);
  }
  if (wg == 0){
    while (__hip_atomic_load(flags + tid, __ATOMIC_RELAXED, __HIP_MEMORY_SCOPE_AGENT) < g)
      __builtin_amdgcn_s_sleep(1);
    __syncthreads();
    if (tid == 0)
      __hip_atomic_store(gen, g, __ATOMIC_RELAXED, __HIP_MEMORY_SCOPE_AGENT);
  } else {
    if (tid == 0){
      while (__hip_atomic_load(gen, __ATOMIC_RELAXED, __HIP_MEMORY_SCOPE_AGENT) < g)
        __builtin_amdgcn_s_sleep(1);
    }
  }
  __syncthreads();
}

// ---------------- threefry2x32 core (bit-exact JAX) ----------------
__device__ __forceinline__ uint32_t rotl32(uint32_t v, int r){ return (v<<r)|(v>>(32-r)); }

__device__ __forceinline__ void tf_block(uint32_t k0, uint32_t k1, uint32_t x0, uint32_t x1,
                                         uint32_t& y0, uint32_t& y1){
  uint32_t k2 = k0 ^ k1 ^ 0x1BD11BDAu;
  x0 += k0; x1 += k1;
#define TF4(r0,r1,r2,r3,ka,kb,inc) \
  x0 += x1; x1 = rotl32(x1,r0); x1 ^= x0; \
  x0 += x1; x1 = rotl32(x1,r1); x1 ^= x0; \
  x0 += x1; x1 = rotl32(x1,r2); x1 ^= x0; \
  x0 += x1; x1 = rotl32(x1,r3); x1 ^= x0; \
  x0 += (ka); x1 += (kb) + (inc);
  TF4(13,15,26,6,  k1,k2,1u)
  TF4(17,29,16,24, k2,k0,2u)
  TF4(13,15,26,6,  k0,k1,3u)
  TF4(17,29,16,24, k1,k2,4u)
  TF4(13,15,26,6,  k2,k0,5u)
#undef TF4
  y0 = x0; y1 = x1;
}

// ---- PARTITIONABLE threefry (jax_threefry_partitionable=True, modern JAX default) ----
__device__ __forceinline__ bool tf_keep_part(uint32_t k0, uint32_t k1, uint32_t i){
  uint32_t y0, y1;
  tf_block(k0, k1, 0u, i, y0, y1);
  return (((y0 ^ y1) >> 31) == 0u);
}

// ---------------- precompute kernels (fp64) ----------------
__global__ __launch_bounds__(TPB) void pm_kernel(
    const float* __restrict__ memory, const float* __restrict__ Wm, double* __restrict__ pmT)
{
  const int bt = blockIdx.x;           // b*400 + t
  const int b = bt / TIN, t2 = bt - b*TIN;
  const int tid = threadIdx.x;
  __shared__ double sm[EDIM];
  __shared__ double sp[TPB];
  for (int i = tid; i < EDIM; i += TPB) sm[i] = (double)memory[(size_t)bt*EDIM + i];
  __syncthreads();
  const int a = tid & 127, hf = tid >> 7;
  const float* w = Wm + (size_t)a*EDIM + hf*256;
  const double* x = sm + hf*256;
  double s = 0.0;
  for (int e = 0; e < 256; ++e) s += (double)w[e]*x[e];
  sp[tid] = s;
  __syncthreads();
  if (tid < ADIM) pmT[((size_t)b*ADIM + tid)*TIN + t2] = sp[tid] + sp[tid+128];
}

__global__ __launch_bounds__(TPB) void wfc_kernel(
    const float* __restrict__ Wd, const float* __restrict__ Wc, double* __restrict__ wfc)
{
  for (int o = threadIdx.x; o < ADIM*62; o += TPB){
    int a = o / 62, ck = o - a*62;
    double s = 0.0;
    for (int f = 0; f < 32; ++f) s += (double)Wd[a*32+f]*(double)Wc[f*62 + ck];
    wfc[o] = s;
  }
}

__global__ void bar_init_kernel(unsigned* bar){
  for (int i = threadIdx.x; i < BAR_UINTS; i += blockDim.x) bar[i] = 0u;
}
__global__ void sentinel_kernel(float* out, float val){ out[0] = val; }

// ---------------- main persistent kernel ----------------
struct DecParams {
  const float *memory, *dec;
  const float *Wpre1, *Wpre2;
  const float *WihA,*WhhA,*bihA,*bhhA;
  const float *Wq,*v;
  const float *WihD,*WhhD,*bihD,*bhhD;
  const float *Wp,*bp,*Wg,*bg;
  const unsigned char* mask;
  double* ws;
  float* out;
};

__device__ __forceinline__ double sigd(double x){ return 1.0/(1.0+exp(-x)); }

__global__ __launch_bounds__(TPB, 1) void decoder_main(DecParams P)
{
  const int wg = blockIdx.x, tid = threadIdx.x;
  const int nwg = GRID_WGS;
  __shared__ __align__(16) double sb[4096];   // 32 KB

  double* ws  = P.ws;
  double* pmT = ws + PM_OFF;   double* wfc = ws + WFC_OFF;
  double* ah  = ws + AH_OFF;   double* ac  = ws + AC_OFF;
  double* dh  = ws + DH_OFF;   double* dc  = ws + DC_OFF;
  double* ctx = ws + CTX_OFF;  double* aw  = ws + AW_OFF;  double* awc = ws + AWC_OFF;
  double* en  = ws + EN_OFF;   double* pq  = ws + PQ_OFF;
  float*  pAf = (float*)(ws + DBL_END);
  float*  pDf = pAf + PDF_OFF;
  unsigned* flags = (unsigned*)(pAf + F_END);
  unsigned* gen   = flags + GEN_IDX;
  unsigned g = 0;

  // zero recurrent state + pre buffers (AH..DBL_END contiguous doubles) via sc1 stores
  for (int i = wg*TPB + tid; i < DBL_END - AH_OFF; i += nwg*TPB) st_d(ah + i, 0.0);
  gridbar(flags, gen, wg, tid, ++g);

  #pragma unroll 1
  for (int t = 0; t <= TOUT; ++t){
    const double* pre_cur = ws + ((t & 1) ? PRE1_OFF : PRE0_OFF);

    // ---- PH1: fp64 gate-GEMM partials (A for step t, D for step t-1) ----
    for (int task = wg; task < NTASK; task += nwg){
      const bool isA = task < NTASK_A;
      if (isA ? (t < TOUT) : (t > 0)){
        int jt, ks;
        if (isA){ jt = task / KSA; ks = task - jt*KSA; }
        else    { int r = task - NTASK_A; jt = r / KSD; ks = r - jt*KSD; }
        const int kbase = ks*256;
        const int jg = tid & 63, bg = tid >> 6;
        const int j0 = jt*256 + jg*4;
        const float* wbase; int rowlen, koff;
        if (isA){
          if (kbase < 768){ wbase = P.WihA; rowlen = 768;  koff = kbase; }
          else            { wbase = P.WhhA; rowlen = 1024; koff = kbase-768; }
        } else {
          if (kbase < 1536){ wbase = P.WihD; rowlen = 1536; koff = kbase; }
          else             { wbase = P.WhhD; rowlen = 1024; koff = kbase-1536; }
        }
        const float* wr0 = wbase + (size_t)(j0+0)*rowlen + koff;
        const float* wr1 = wbase + (size_t)(j0+1)*rowlen + koff;
        const float* wr2 = wbase + (size_t)(j0+2)*rowlen + koff;
        const float* wr3 = wbase + (size_t)(j0+3)*rowlen + koff;
        double acc[32];
        #pragma unroll
        for (int i = 0; i < 32; ++i) acc[i] = 0.0;

        #pragma unroll 1
        for (int half = 0; half < 2; ++half){
          const int kb2 = kbase + half*128;
          if (isA){
            for (int i = tid; i < NB*128; i += TPB){
              const int b = i >> 7, kg = kb2 + (i & 127);
              double xv;
              if (kg < 256)       xv = ld_d(pre_cur + (b<<8) + kg);
              else if (kg < 768)  xv = ld_d(ctx + b*EDIM + (kg-256));
              else                xv = ld_d(ah + b*ARNN + (kg-768));
              sb[i] = xv;
            }
          } else {
            for (int i = tid; i < NB*128; i += TPB){
              const int b = i >> 7, kg = kb2 + (i & 127);
              double xv;
              if (kg < 1024)      xv = ld_d(ah + b*ARNN + kg);
              else if (kg < 1536) xv = ld_d(ctx + b*EDIM + (kg-1024));
              else                xv = ld_d(dh + b*ARNN + (kg-1536));
              sb[i] = xv;
            }
          }
          __syncthreads();
          const int kadd = half*128;
          #pragma unroll 1
          for (int kk = 0; kk < 128; kk += 4){
            const float4 f0 = *(const float4*)(wr0 + kadd + kk);
            const float4 f1 = *(const float4*)(wr1 + kadd + kk);
            const float4 f2 = *(const float4*)(wr2 + kadd + kk);
            const float4 f3 = *(const float4*)(wr3 + kadd + kk);
            const double w00=f0.x,w01=f0.y,w02=f0.z,w03=f0.w;
            const double w10=f1.x,w11=f1.y,w12=f1.z,w13=f1.w;
            const double w20=f2.x,w21=f2.y,w22=f2.z,w23=f2.w;
            const double w30=f3.x,w31=f3.y,w32=f3.z,w33=f3.w;
            #pragma unroll
            for (int bi = 0; bi < 8; ++bi){
              const double* xp = sb + (((bg<<3)+bi)<<7) + kk;
              const double x0=xp[0], x1=xp[1], x2=xp[2], x3=xp[3];
              acc[bi*4+0] += w00*x0 + w01*x1 + w02*x2 + w03*x3;
              acc[bi*4+1] += w10*x0 + w11*x1 + w12*x2 + w13*x3;
              acc[bi*4+2] += w20*x0 + w21*x1 + w22*x2 + w23*x3;
              acc[bi*4+3] += w30*x0 + w31*x1 + w32*x2 + w33*x3;
            }
          }
          __syncthreads();
        }

        float* pbase = (isA ? pAf : pDf) + ((size_t)ks*NB)*NGATE;
        #pragma unroll
        for (int bi = 0; bi < 8; ++bi){
          const int b = (bg<<3) + bi;
          float* pp = pbase + (size_t)b*NGATE + j0;
          st_f2(pp,   (float)acc[bi*4+0], (float)acc[bi*4+1]);
          st_f2(pp+2, (float)acc[bi*4+2], (float)acc[bi*4+3]);
        }
      }
    }
    gridbar(flags, gen, wg, tid, ++g);

    // ---- PH1b: LSTM reduce + activations (+ pq = Wq @ ah), fp64 ----
    if (wg < NB){
      if (t < TOUT){
        const int b = wg;
        for (int h = tid; h < ARNN; h += TPB){
          double g0 = (double)P.bihA[h]      + (double)P.bhhA[h];
          double g1 = (double)P.bihA[1024+h] + (double)P.bhhA[1024+h];
          double g2 = (double)P.bihA[2048+h] + (double)P.bhhA[2048+h];
          double g3 = (double)P.bihA[3072+h] + (double)P.bhhA[3072+h];
          for (int p2 = 0; p2 < KSA; ++p2){
            const float* pp = pAf + ((size_t)p2*NB + b)*NGATE;
            g0 += (double)ld_f(pp + h);        g1 += (double)ld_f(pp + 1024 + h);
            g2 += (double)ld_f(pp + 2048 + h); g3 += (double)ld_f(pp + 3072 + h);
          }
          const double cp = ac[b*ARNN + h];
          const double cn = sigd(g1)*cp + sigd(g0)*tanh(g2);
          const double hn = sigd(g3)*tanh(cn);
          ac[b*ARNN+h] = cn;             // private to this WG: normal cached access
          st_d(ah + b*ARNN + h, hn);     // shared: sc1
          sb[h] = hn;
        }
        __syncthreads();
        {
          const int a2 = tid >> 1, hf = tid & 1;
          const float* wq = P.Wq + (size_t)a2*ARNN + hf*512;
          const double* xh = sb + hf*512;
          double s = 0.0;
          for (int h2 = 0; h2 < 512; ++h2) s += (double)wq[h2]*xh[h2];
          sb[1024 + tid] = s;
        }
        __syncthreads();
        if (tid < ADIM) st_d(pq + b*ADIM + tid, sb[1024 + 2*tid] + sb[1024 + 2*tid + 1]);
      }
    } else if (wg < 2*NB){
      if (t > 0){
        const int b = wg - NB;
        for (int h = tid; h < ARNN; h += TPB){
          double g0 = (double)P.bihD[h]      + (double)P.bhhD[h];
          double g1 = (double)P.bihD[1024+h] + (double)P.bhhD[1024+h];
          double g2 = (double)P.bihD[2048+h] + (double)P.bhhD[2048+h];
          double g3 = (double)P.bihD[3072+h] + (double)P.bhhD[3072+h];
          for (int p2 = 0; p2 < KSD; ++p2){
            const float* pp = pDf + ((size_t)p2*NB + b)*NGATE;
            g0 += (double)ld_f(pp + h);        g1 += (double)ld_f(pp + 1024 + h);
            g2 += (double)ld_f(pp + 2048 + h); g3 += (double)ld_f(pp + 3072 + h);
          }
          const double cp = dc[b*ARNN + h];
          const double cn = sigd(g1)*cp + sigd(g0)*tanh(g2);
          const double hn = sigd(g3)*tanh(cn);
          dc[b*ARNN+h] = cn;             // private: normal
          st_d(dh + b*ARNN + h, hn);     // shared: sc1
        }
      }
    }
    gridbar(flags, gen, wg, tid, ++g);

    // ---- PH2: attention energies (t) + mel/gate (t-1), fp64 ----
    if (wg < 224){
      if (t < TOUT){
        const int b = wg / 7, tt = wg - b*7;
        const int tbase = tt*64;
        if (tid < ADIM) sb[tid] = ld_d(pq + b*ADIM + tid);
        for (int i = tid; i < 94; i += TPB){
          int tg = tbase - 15 + i;
          sb[128 + i] = (tg >= 0 && tg < TIN) ? ld_d(aw + b*TIN + tg) : 0.0;
        }
        for (int i = tid; i < 94; i += TPB){
          int tg = tbase - 15 + i;
          sb[222 + i] = (tg >= 0 && tg < TIN) ? ld_d(awc + b*TIN + tg) : 0.0;
        }
        __syncthreads();
        const int wv = tid >> 6, lane = tid & 63;
        const int tg = tbase + lane;
        double esum = 0.0;
        if (tg < TIN){
          double w0r[31], w1r[31];
          #pragma unroll
          for (int k = 0; k < 31; ++k){ w0r[k] = sb[128 + lane + k]; w1r[k] = sb[222 + lane + k]; }
          const double* pmrow = pmT + (size_t)b*ADIM*TIN + tg;
          for (int a2 = wv*32; a2 < wv*32 + 32; ++a2){
            const double* wf = wfc + a2*62;
            double cv = 0.0;
            #pragma unroll
            for (int k = 0; k < 31; ++k) cv += wf[k]*w0r[k];
            #pragma unroll
            for (int k = 0; k < 31; ++k) cv += wf[31+k]*w1r[k];
            const double e = sb[a2] + cv + pmrow[(size_t)a2*TIN];
            esum += (double)P.v[a2]*tanh(e);
          }
        }
        sb[640 + wv*64 + lane] = esum;
        __syncthreads();
        if (tid < 64){
          const int tg2 = tbase + tid;
          if (tg2 < TIN){
            double e = sb[640+tid] + sb[704+tid] + sb[768+tid] + sb[832+tid];
            if (P.mask[b*TIN + tg2]) e = -1e9;
            st_d(en + b*TIN + tg2, e);
          }
        }
      }
    } else if (wg < 256){
      if (t > 0){
        const int b = wg - 224, ts = t-1;
        for (int i = tid; i < 1536; i += TPB)
          sb[i] = (i < 1024) ? ld_d(dh + b*ARNN + i) : ld_d(ctx + b*EDIM + (i-1024));
        __syncthreads();
        const int o = tid >> 1, hf = tid & 1;
        double s = 0.0;
        if (o <= 80){
          const float* wr = ((o < 80) ? (P.Wp + (size_t)o*1536) : P.Wg) + hf*768;
          const double* xr = sb + hf*768;
          for (int m2 = 0; m2 < 768; ++m2) s += (double)wr[m2]*xr[m2];
        }
        sb[1600 + tid] = s;
        __syncthreads();
        if (tid <= 80){
          double val = sb[1600 + 2*tid] + sb[1600 + 2*tid + 1];
          if (tid < 80) P.out[MEL_OFF + ((size_t)b*NMEL + tid)*TOUT + ts] = (float)(val + (double)P.bp[tid]);
          else          P.out[GATE_OFF + (size_t)b*TOUT + ts] = (float)(val + (double)P.bg[0]);
        }
      }
    }
    gridbar(flags, gen, wg, tid, ++g);

    // ---- PH3: softmax + context (WGs 0..31) | prenet t+1 (WGs 32..63), fp64 ----
    if (wg < NB){
      if (t < TOUT){
        const int b = wg;
        double m = -1.0e300;
        for (int i = tid; i < TIN; i += TPB){
          double e = ld_d(en + b*TIN + i);
          sb[512 + i] = e;                    // stash: single sc1 pass over en
          m = fmax(m, e);
        }
        sb[tid] = m; __syncthreads();
        for (int s2 = TPB/2; s2 > 0; s2 >>= 1){
          if (tid < s2) sb[tid] = fmax(sb[tid], sb[tid+s2]);
          __syncthreads();
        }
        const double mx = sb[0];
        __syncthreads();
        double ssum = 0.0;
        for (int i = tid; i < TIN; i += TPB){
          double u = exp(sb[512+i] - mx);
          sb[512 + i] = u; ssum += u;
        }
        sb[tid] = ssum; __syncthreads();
        for (int s2 = TPB/2; s2 > 0; s2 >>= 1){
          if (tid < s2) sb[tid] += sb[tid+s2];
          __syncthreads();
        }
        const double tot = sb[0];
        __syncthreads();
        for (int i = tid; i < TIN; i += TPB){
          double a2 = sb[512+i] / tot;
          sb[512+i] = a2;
          st_d(aw + b*TIN + i, a2);
          st_d(awc + b*TIN + i, ld_d(awc + b*TIN + i) + a2);
          P.out[AL_OFF + ((size_t)b*TOUT + t)*TIN + i] = (float)a2;
        }
        __syncthreads();
        for (int e2 = tid; e2 < EDIM; e2 += TPB){
          const float* mrow = P.memory + (size_t)b*TIN*EDIM + e2;
          double s = 0.0;
          for (int t2 = 0; t2 < TIN; ++t2) s += sb[512+t2]*(double)mrow[(size_t)t2*EDIM];
          st_d(ctx + b*EDIM + e2, s);
        }
      }
    } else if (wg < 2*NB){
      if (t < TOUT-1){
        const int b = wg - NB, t1 = t + 1;
        double* pre_next = ws + ((t1 & 1) ? PRE1_OFF : PRE0_OFF);
        for (int m = tid; m < NMEL; m += TPB)
          sb[m] = (double)P.dec[((size_t)b*NMEL + m)*TOUT + (t1-1)];
        __syncthreads();
        // PARTITIONABLE split of key(42)=(0,42): dk_i = full output of block(0, i)
        uint32_t d1k0, d1k1, d2k0, d2k1;
        tf_block(0u, 42u, 0u, 0u, d1k0, d1k1);   // dk1 = (y0, y1) @ counter 0
        tf_block(0u, 42u, 0u, 1u, d2k0, d2k1);   // dk2 = (y0, y1) @ counter 1
        const uint32_t flat = ((uint32_t)(t1*NB + b))*PDIM + tid;
        {
          const float* w = P.Wpre1 + tid*NMEL;
          double s = 0.0;
          for (int m = 0; m < NMEL; ++m) s += sb[m]*(double)w[m];
          double hv = tf_keep_part(d1k0, d1k1, flat) ? s*2.0 : 0.0;
          sb[128 + tid] = fmax(hv, 0.0);
        }
        __syncthreads();
        {
          const float* w = P.Wpre2 + tid*PDIM;
          double s = 0.0;
          for (int m = 0; m < PDIM; ++m) s += sb[128+m]*(double)w[m];
          double pv = tf_keep_part(d2k0, d2k1, flat) ? s*2.0 : 0.0;
          st_d(pre_next + (b<<8) + tid, fmax(pv, 0.0));
        }
      }
    }
    gridbar(flags, gen, wg, tid, ++g);
  }
}

extern "C" void kernel_launch(void* const* d_in, const int* in_sizes, int n_in,
                              void* d_out, int out_size, void* d_ws, size_t ws_size,
                              hipStream_t stream)
{
  const float* memory = (const float*)d_in[0];
  const float* dec    = (const float*)d_in[1];
  const unsigned char* mask = (const unsigned char*)d_in[2];
  const float* W_pre1 = (const float*)d_in[3];
  const float* W_pre2 = (const float*)d_in[4];
  const float* WihA   = (const float*)d_in[5];
  const float* WhhA   = (const float*)d_in[6];
  const float* bihA   = (const float*)d_in[7];
  const float* bhhA   = (const float*)d_in[8];
  const float* Wq     = (const float*)d_in[9];
  const float* Wm     = (const float*)d_in[10];
  const float* v      = (const float*)d_in[11];
  const float* Wc     = (const float*)d_in[12];
  const float* Wd     = (const float*)d_in[13];
  const float* WihD   = (const float*)d_in[14];
  const float* WhhD   = (const float*)d_in[15];
  const float* bihD   = (const float*)d_in[16];
  const float* bhhD   = (const float*)d_in[17];
  const float* Wp     = (const float*)d_in[18];
  const float* bp     = (const float*)d_in[19];
  const float* Wg     = (const float*)d_in[20];
  const float* bg     = (const float*)d_in[21];

  double* ws = (double*)d_ws;
  float* out = (float*)d_out;

  if (ws_size < WS_BYTES){
    sentinel_kernel<<<1, 1, 0, stream>>>(out, 12345.0f);   // diagnostic: ws too small
    return;
  }

  unsigned* bar = (unsigned*)((float*)(ws + DBL_END) + F_END);
  bar_init_kernel<<<1, TPB, 0, stream>>>(bar);
  pm_kernel<<<NB*TIN, TPB, 0, stream>>>(memory, Wm, ws + PM_OFF);
  wfc_kernel<<<1, TPB, 0, stream>>>(Wd, Wc, ws + WFC_OFF);

  DecParams P;
  P.memory = memory; P.dec = dec;
  P.Wpre1 = W_pre1; P.Wpre2 = W_pre2;
  P.WihA = WihA; P.WhhA = WhhA; P.bihA = bihA; P.bhhA = bhhA;
  P.Wq = Wq; P.v = v;
  P.WihD = WihD; P.WhhD = WhhD; P.bihD = bihD; P.bhhD = bhhD;
  P.Wp = Wp; P.bp = bp; P.Wg = Wg; P.bg = bg;
  P.mask = mask; P.ws = ws; P.out = out;

  decoder_main<<<GRID_WGS, TPB, 0, stream>>>(P);
}

// Round 5
// 97979.254 us; speedup vs baseline: 4.0234x; 1.9784x over previous
//
#include <hip/hip_runtime.h>
#include <cstdint>

#define TPB 256
#define GRID_WGS 256

// problem dims
#define NB    32
#define TIN   400
#define TOUT  500
#define NMEL  80
#define EDIM  512
#define ARNN  1024
#define PDIM  256
#define ADIM  128
#define NGATE 4096

#define KSA 7        // attention-LSTM K = 1792 = 7 x 256 (2 pieces of 128)
#define KSD 8        // decoder-LSTM   K = 2560 = 8 x 320 (pieces 128+128+64)
#define NTASK_A 112  // 16 j-tiles x 7 k-chunks
#define NTASK   240  // + 16 j-tiles x 8 k-chunks  -> <=1 task per WG (balanced)

// double-region offsets (units: doubles)
#define PM_OFF   0          // pmT[b][a][t] [32][128][400]
#define WFC_OFF  1638400    // [128][62]
#define AH_OFF   1646336
#define AC_OFF   1679104
#define DH_OFF   1711872
#define DC_OFF   1744640
#define CTX_OFF  1777408
#define AW_OFF   1793792
#define AWC_OFF  1806592
#define EN_OFF   1819392
#define PQ_OFF   1832192
#define PRE0_OFF 1836288
#define PRE1_OFF 1844480
#define DBL_END  1852672
// float region (units: floats, base = (float*)(ws + DBL_END))
#define PAF_OFF  0          // A partials [7][32][4096]
#define PDF_OFF  917504     // D partials [8][32][4096]
#define F_END    1966080
// barrier region after float region: flags[256] (4B each) + gen at its own line
#define BAR_UINTS 320       // 1280 B: flags[0..255], gen at [256] (byte 1024, own 128B line)
#define GEN_IDX   256
#define WS_BYTES ((size_t)DBL_END*8 + (size_t)F_END*4 + (size_t)BAR_UINTS*4)

#define MEL_OFF  0
#define GATE_OFF 1280000
#define AL_OFF   1296000

// ---------------- agent-coherent (sc1, coherence-point) access wrappers ----------------
__device__ __forceinline__ double ld_d(const double* p){
  return __hip_atomic_load(p, __ATOMIC_RELAXED, __HIP_MEMORY_SCOPE_AGENT);
}
__device__ __forceinline__ void st_d(double* p, double v){
  __hip_atomic_store(p, v, __ATOMIC_RELAXED, __HIP_MEMORY_SCOPE_AGENT);
}
__device__ __forceinline__ float ld_f(const float* p){
  return __hip_atomic_load(p, __ATOMIC_RELAXED, __HIP_MEMORY_SCOPE_AGENT);
}
__device__ __forceinline__ void st_f2(float* p, float a, float b){
  union { float f[2]; unsigned long long u; } x; x.f[0] = a; x.f[1] = b;
  __hip_atomic_store(reinterpret_cast<unsigned long long*>(p), x.u,
                     __ATOMIC_RELAXED, __HIP_MEMORY_SCOPE_AGENT);
}

// ---------------- flag-array grid barrier (round-3-proven form, all relaxed) -----------
// Arrival: each WG's tid0 stores generation g to its OWN flag word (parallel at the
// coherence point). WG0's 256 threads poll the 256 flags, then WG0 publishes gen=g;
// other WGs poll gen (same-line broadcast reads). Monotone generations, no resets,
// no cross-address ordering requirement -> all relaxed -> zero cache maintenance.
__device__ __forceinline__ void gridbar(unsigned* flags, unsigned* gen, int wg, int tid, unsigned g){
  __syncthreads();
  if (tid == 0){
    asm volatile("s_waitcnt vmcnt(0) lgkmcnt(0)" ::: "memory");
    __hip_atomic_store(flags + wg, g, __ATOMIC_RELAXED, __HIP_MEMORY_SCOPE_AGENT);
  }
  if (wg == 0){
    while (__hip_atomic_load(flags + tid, __ATOMIC_RELAXED, __HIP_MEMORY_SCOPE_AGENT) < g)
      __builtin_amdgcn_s_sleep(1);
    __syncthreads();
    if (tid == 0)
      __hip_atomic_store(gen, g, __ATOMIC_RELAXED, __HIP_MEMORY_SCOPE_AGENT);
  } else {
    if (tid == 0){
      while (__hip_atomic_load(gen, __ATOMIC_RELAXED, __HIP_MEMORY_SCOPE_AGENT) < g)
        __builtin_amdgcn_s_sleep(1);
    }
  }
  __syncthreads();
}

// ---------------- threefry2x32 core (bit-exact JAX) ----------------
__device__ __forceinline__ uint32_t rotl32(uint32_t v, int r){ return (v<<r)|(v>>(32-r)); }

__device__ __forceinline__ void tf_block(uint32_t k0, uint32_t k1, uint32_t x0, uint32_t x1,
                                         uint32_t& y0, uint32_t& y1){
  uint32_t k2 = k0 ^ k1 ^ 0x1BD11BDAu;
  x0 += k0; x1 += k1;
#define TF4(r0,r1,r2,r3,ka,kb,inc) \
  x0 += x1; x1 = rotl32(x1,r0); x1 ^= x0; \
  x0 += x1; x1 = rotl32(x1,r1); x1 ^= x0; \
  x0 += x1; x1 = rotl32(x1,r2); x1 ^= x0; \
  x0 += x1; x1 = rotl32(x1,r3); x1 ^= x0; \
  x0 += (ka); x1 += (kb) + (inc);
  TF4(13,15,26,6,  k1,k2,1u)
  TF4(17,29,16,24, k2,k0,2u)
  TF4(13,15,26,6,  k0,k1,3u)
  TF4(17,29,16,24, k1,k2,4u)
  TF4(13,15,26,6,  k2,k0,5u)
#undef TF4
  y0 = x0; y1 = x1;
}

__device__ __forceinline__ bool tf_keep_part(uint32_t k0, uint32_t k1, uint32_t i){
  uint32_t y0, y1;
  tf_block(k0, k1, 0u, i, y0, y1);
  return (((y0 ^ y1) >> 31) == 0u);
}

// ---------------- precompute kernels (fp64) ----------------
__global__ __launch_bounds__(TPB) void pm_kernel(
    const float* __restrict__ memory, const float* __restrict__ Wm, double* __restrict__ pmT)
{
  const int bt = blockIdx.x;           // b*400 + t
  const int b = bt / TIN, t2 = bt - b*TIN;
  const int tid = threadIdx.x;
  __shared__ double sm[EDIM];
  __shared__ double sp[TPB];
  for (int i = tid; i < EDIM; i += TPB) sm[i] = (double)memory[(size_t)bt*EDIM + i];
  __syncthreads();
  const int a = tid & 127, hf = tid >> 7;
  const float* w = Wm + (size_t)a*EDIM + hf*256;
  const double* x = sm + hf*256;
  double s = 0.0;
  for (int e = 0; e < 256; ++e) s += (double)w[e]*x[e];
  sp[tid] = s;
  __syncthreads();
  if (tid < ADIM) pmT[((size_t)b*ADIM + tid)*TIN + t2] = sp[tid] + sp[tid+128];
}

__global__ __launch_bounds__(TPB) void wfc_kernel(
    const float* __restrict__ Wd, const float* __restrict__ Wc, double* __restrict__ wfc)
{
  for (int o = threadIdx.x; o < ADIM*62; o += TPB){
    int a = o / 62, ck = o - a*62;
    double s = 0.0;
    for (int f = 0; f < 32; ++f) s += (double)Wd[a*32+f]*(double)Wc[f*62 + ck];
    wfc[o] = s;
  }
}

__global__ void bar_init_kernel(unsigned* bar){
  for (int i = threadIdx.x; i < BAR_UINTS; i += blockDim.x) bar[i] = 0u;
}
__global__ void sentinel_kernel(float* out, float val){ out[0] = val; }

// ---------------- main persistent kernel ----------------
struct DecParams {
  const float *memory, *dec;
  const float *Wpre1, *Wpre2;
  const float *WihA,*WhhA,*bihA,*bhhA;
  const float *Wq,*v;
  const float *WihD,*WhhD,*bihD,*bhhD;
  const float *Wp,*bp,*Wg,*bg;
  const unsigned char* mask;
  double* ws;
  float* out;
};

__device__ __forceinline__ double sigd(double x){ return 1.0/(1.0+exp(-x)); }

// 4 outputs x 8 k fp64 FMA block (w?? scalars must be in scope)
#define ROWFMA(a0,a1,a2,a3, xp) do{ \
  const double x0=(xp)[0],x1=(xp)[1],x2=(xp)[2],x3=(xp)[3], \
               x4=(xp)[4],x5=(xp)[5],x6=(xp)[6],x7=(xp)[7]; \
  a0 += w00*x0+w01*x1+w02*x2+w03*x3+w04*x4+w05*x5+w06*x6+w07*x7; \
  a1 += w10*x0+w11*x1+w12*x2+w13*x3+w14*x4+w15*x5+w16*x6+w17*x7; \
  a2 += w20*x0+w21*x1+w22*x2+w23*x3+w24*x4+w25*x5+w26*x6+w27*x7; \
  a3 += w30*x0+w31*x1+w32*x2+w33*x3+w34*x4+w35*x5+w36*x6+w37*x7; \
}while(0)

__global__ __launch_bounds__(TPB, 1) void decoder_main(DecParams P)
{
  const int wg = blockIdx.x, tid = threadIdx.x;
  const int nwg = GRID_WGS;
  __shared__ __align__(16) double sb[4096];   // 32 KB

  double* ws  = P.ws;
  double* pmT = ws + PM_OFF;   double* wfc = ws + WFC_OFF;
  double* ah  = ws + AH_OFF;   double* ac  = ws + AC_OFF;
  double* dh  = ws + DH_OFF;   double* dc  = ws + DC_OFF;
  double* ctx = ws + CTX_OFF;  double* aw  = ws + AW_OFF;  double* awc = ws + AWC_OFF;
  double* en  = ws + EN_OFF;   double* pq  = ws + PQ_OFF;
  float*  pAf = (float*)(ws + DBL_END);
  float*  pDf = pAf + PDF_OFF;
  unsigned* flags = (unsigned*)(pAf + F_END);
  unsigned* gen   = flags + GEN_IDX;
  unsigned g = 0;

  // zero recurrent state + pre buffers via sc1 stores
  for (int i = wg*TPB + tid; i < DBL_END - AH_OFF; i += nwg*TPB) st_d(ah + i, 0.0);
  gridbar(flags, gen, wg, tid, ++g);

  #pragma unroll 1
  for (int t = 0; t <= TOUT; ++t){
    const double* pre_cur = ws + ((t & 1) ? PRE1_OFF : PRE0_OFF);

    // ---- PH1: fp64 gate-GEMM partials (A for step t, D for step t-1), prefetched ----
    if (wg < NTASK){
      const bool isA = wg < NTASK_A;
      if (isA ? (t < TOUT) : (t > 0)){
        int jt, ks, kbase;
        if (isA){ jt = wg / KSA; ks = wg - jt*KSA; kbase = ks*256; }
        else    { int r = wg - NTASK_A; jt = r >> 3; ks = r & 7; kbase = ks*320; }
        const int jg = tid & 63, bgi = tid >> 6;
        const int j0 = jt*256 + jg*4;
        double acc[32];
        #pragma unroll
        for (int i = 0; i < 32; ++i) acc[i] = 0.0;

        const int npieces = isA ? 2 : 3;
        #pragma unroll 1
        for (int pc = 0; pc < npieces; ++pc){
          const int poff = pc*128;
          const int len  = (isA || pc < 2) ? 128 : 64;
          const int kb2  = kbase + poff;
          // stage x[b][k] for this piece into sb[b*128 + kloc] (sc1 state reads)
          if (isA){
            for (int i = tid; i < NB*128; i += TPB){
              const int b = i >> 7, kloc = i & 127, kg = kb2 + kloc;
              double xv;
              if (kg < 256)       xv = ld_d(pre_cur + (b<<8) + kg);
              else if (kg < 768)  xv = ld_d(ctx + b*EDIM + (kg-256));
              else                xv = ld_d(ah + b*ARNN + (kg-768));
              sb[(b<<7) + kloc] = xv;
            }
          } else if (len == 128){
            for (int i = tid; i < NB*128; i += TPB){
              const int b = i >> 7, kloc = i & 127, kg = kb2 + kloc;
              double xv;
              if (kg < 1024)      xv = ld_d(ah + b*ARNN + kg);
              else if (kg < 1536) xv = ld_d(ctx + b*EDIM + (kg-1024));
              else                xv = ld_d(dh + b*ARNN + (kg-1536));
              sb[(b<<7) + kloc] = xv;
            }
          } else {
            for (int i = tid; i < NB*64; i += TPB){
              const int b = i >> 6, kloc = i & 63, kg = kb2 + kloc;
              double xv;
              if (kg < 1024)      xv = ld_d(ah + b*ARNN + kg);
              else if (kg < 1536) xv = ld_d(ctx + b*EDIM + (kg-1024));
              else                xv = ld_d(dh + b*ARNN + (kg-1536));
              sb[(b<<7) + kloc] = xv;
            }
          }
          __syncthreads();
          // weight rows for this piece (pieces never straddle the ih/hh boundary)
          const float* wbase; int rowlen, koff;
          if (isA){
            if (kb2 < 768){ wbase = P.WihA; rowlen = 768;  koff = kb2; }
            else          { wbase = P.WhhA; rowlen = 1024; koff = kb2-768; }
          } else {
            if (kb2 < 1536){ wbase = P.WihD; rowlen = 1536; koff = kb2; }
            else           { wbase = P.WhhD; rowlen = 1024; koff = kb2-1536; }
          }
          const float* w0p = wbase + (size_t)(j0+0)*rowlen + koff;
          const float* w1p = wbase + (size_t)(j0+1)*rowlen + koff;
          const float* w2p = wbase + (size_t)(j0+2)*rowlen + koff;
          const float* w3p = wbase + (size_t)(j0+3)*rowlen + koff;
          // 1-deep register prefetch: load k-block kk+8 while computing kk
          float4 c00=*(const float4*)(w0p),   c01=*(const float4*)(w0p+4);
          float4 c10=*(const float4*)(w1p),   c11=*(const float4*)(w1p+4);
          float4 c20=*(const float4*)(w2p),   c21=*(const float4*)(w2p+4);
          float4 c30=*(const float4*)(w3p),   c31=*(const float4*)(w3p+4);
          #pragma unroll 1
          for (int kk = 0; kk < len; kk += 8){
            const int kn = (kk + 8 < len) ? (kk + 8) : kk;   // clamp: last iter reloads
            float4 n00=*(const float4*)(w0p+kn), n01=*(const float4*)(w0p+kn+4);
            float4 n10=*(const float4*)(w1p+kn), n11=*(const float4*)(w1p+kn+4);
            float4 n20=*(const float4*)(w2p+kn), n21=*(const float4*)(w2p+kn+4);
            float4 n30=*(const float4*)(w3p+kn), n31=*(const float4*)(w3p+kn+4);
            {
              const double w00=c00.x,w01=c00.y,w02=c00.z,w03=c00.w,
                           w04=c01.x,w05=c01.y,w06=c01.z,w07=c01.w;
              const double w10=c10.x,w11=c10.y,w12=c10.z,w13=c10.w,
                           w14=c11.x,w15=c11.y,w16=c11.z,w17=c11.w;
              const double w20=c20.x,w21=c20.y,w22=c20.z,w23=c20.w,
                           w24=c21.x,w25=c21.y,w26=c21.z,w27=c21.w;
              const double w30=c30.x,w31=c30.y,w32=c30.z,w33=c30.w,
                           w34=c31.x,w35=c31.y,w36=c31.z,w37=c31.w;
              const double* xb = sb + kk;
              #pragma unroll
              for (int bi = 0; bi < 8; ++bi){
                const double* xp = xb + (((bgi<<3)+bi)<<7);
                ROWFMA(acc[bi*4+0],acc[bi*4+1],acc[bi*4+2],acc[bi*4+3], xp);
              }
            }
            c00=n00;c01=n01;c10=n10;c11=n11;c20=n20;c21=n21;c30=n30;c31=n31;
          }
          __syncthreads();
        }

        float* pbase = (isA ? pAf : pDf) + ((size_t)ks*NB)*NGATE;
        #pragma unroll
        for (int bi = 0; bi < 8; ++bi){
          const int b = (bgi<<3) + bi;
          float* pp = pbase + (size_t)b*NGATE + j0;
          st_f2(pp,   (float)acc[bi*4+0], (float)acc[bi*4+1]);
          st_f2(pp+2, (float)acc[bi*4+2], (float)acc[bi*4+3]);
        }
      }
    }
    gridbar(flags, gen, wg, tid, ++g);

    // ---- PH1b: LSTM reduce + activations (+ pq), and prenet(t+1) on WGs 64..95 ----
    if (wg < NB){
      if (t < TOUT){
        const int b = wg;
        for (int h = tid; h < ARNN; h += TPB){
          double g0 = (double)P.bihA[h]      + (double)P.bhhA[h];
          double g1 = (double)P.bihA[1024+h] + (double)P.bhhA[1024+h];
          double g2 = (double)P.bihA[2048+h] + (double)P.bhhA[2048+h];
          double g3 = (double)P.bihA[3072+h] + (double)P.bhhA[3072+h];
          for (int p2 = 0; p2 < KSA; ++p2){
            const float* pp = pAf + ((size_t)p2*NB + b)*NGATE;
            g0 += (double)ld_f(pp + h);        g1 += (double)ld_f(pp + 1024 + h);
            g2 += (double)ld_f(pp + 2048 + h); g3 += (double)ld_f(pp + 3072 + h);
          }
          const double cp = ac[b*ARNN + h];
          const double cn = sigd(g1)*cp + sigd(g0)*tanh(g2);
          const double hn = sigd(g3)*tanh(cn);
          ac[b*ARNN+h] = cn;             // private: normal cached
          st_d(ah + b*ARNN + h, hn);     // shared: sc1
          sb[h] = hn;
        }
        __syncthreads();
        {
          const int a2 = tid >> 1, hf = tid & 1;
          const float* wq = P.Wq + (size_t)a2*ARNN + hf*512;
          const double* xh = sb + hf*512;
          double s = 0.0;
          for (int h2 = 0; h2 < 512; ++h2) s += (double)wq[h2]*xh[h2];
          sb[1024 + tid] = s;
        }
        __syncthreads();
        if (tid < ADIM) st_d(pq + b*ADIM + tid, sb[1024 + 2*tid] + sb[1024 + 2*tid + 1]);
      }
    } else if (wg < 2*NB){
      if (t > 0){
        const int b = wg - NB;
        for (int h = tid; h < ARNN; h += TPB){
          double g0 = (double)P.bihD[h]      + (double)P.bhhD[h];
          double g1 = (double)P.bihD[1024+h] + (double)P.bhhD[1024+h];
          double g2 = (double)P.bihD[2048+h] + (double)P.bhhD[2048+h];
          double g3 = (double)P.bihD[3072+h] + (double)P.bhhD[3072+h];
          for (int p2 = 0; p2 < KSD; ++p2){
            const float* pp = pDf + ((size_t)p2*NB + b)*NGATE;
            g0 += (double)ld_f(pp + h);        g1 += (double)ld_f(pp + 1024 + h);
            g2 += (double)ld_f(pp + 2048 + h); g3 += (double)ld_f(pp + 3072 + h);
          }
          const double cp = dc[b*ARNN + h];
          const double cn = sigd(g1)*cp + sigd(g0)*tanh(g2);
          const double hn = sigd(g3)*tanh(cn);
          dc[b*ARNN+h] = cn;             // private: normal
          st_d(dh + b*ARNN + h, hn);     // shared: sc1
        }
      }
    } else if (wg < 3*NB){
      if (t < TOUT-1){
        // prenet for step t+1 (depends only on dec input; PRE double-buffer by parity)
        const int b = wg - 2*NB, t1 = t + 1;
        double* pre_next = ws + ((t1 & 1) ? PRE1_OFF : PRE0_OFF);
        for (int m = tid; m < NMEL; m += TPB)
          sb[m] = (double)P.dec[((size_t)b*NMEL + m)*TOUT + (t1-1)];
        __syncthreads();
        uint32_t d1k0, d1k1, d2k0, d2k1;
        tf_block(0u, 42u, 0u, 0u, d1k0, d1k1);
        tf_block(0u, 42u, 0u, 1u, d2k0, d2k1);
        const uint32_t flat = ((uint32_t)(t1*NB + b))*PDIM + tid;
        {
          const float* w = P.Wpre1 + tid*NMEL;
          double s = 0.0;
          for (int m = 0; m < NMEL; ++m) s += sb[m]*(double)w[m];
          double hv = tf_keep_part(d1k0, d1k1, flat) ? s*2.0 : 0.0;
          sb[128 + tid] = fmax(hv, 0.0);
        }
        __syncthreads();
        {
          const float* w = P.Wpre2 + tid*PDIM;
          double s = 0.0;
          for (int m = 0; m < PDIM; ++m) s += sb[128+m]*(double)w[m];
          double pv = tf_keep_part(d2k0, d2k1, flat) ? s*2.0 : 0.0;
          st_d(pre_next + (b<<8) + tid, fmax(pv, 0.0));
        }
      }
    }
    gridbar(flags, gen, wg, tid, ++g);

    // ---- PH2: attention energies (t) + mel/gate (t-1), fp64 ----
    if (wg < 224){
      if (t < TOUT){
        const int b = wg / 7, tt = wg - b*7;
        const int tbase = tt*64;
        if (tid < ADIM) sb[tid] = ld_d(pq + b*ADIM + tid);
        for (int i = tid; i < 94; i += TPB){
          int tg = tbase - 15 + i;
          sb[128 + i] = (tg >= 0 && tg < TIN) ? ld_d(aw + b*TIN + tg) : 0.0;
        }
        for (int i = tid; i < 94; i += TPB){
          int tg = tbase - 15 + i;
          sb[222 + i] = (tg >= 0 && tg < TIN) ? ld_d(awc + b*TIN + tg) : 0.0;
        }
        __syncthreads();
        const int wv = tid >> 6, lane = tid & 63;
        const int tg = tbase + lane;
        double esum = 0.0;
        if (tg < TIN){
          double w0r[31], w1r[31];
          #pragma unroll
          for (int k = 0; k < 31; ++k){ w0r[k] = sb[128 + lane + k]; w1r[k] = sb[222 + lane + k]; }
          const double* pmrow = pmT + (size_t)b*ADIM*TIN + tg;
          for (int a2 = wv*32; a2 < wv*32 + 32; ++a2){
            const double* wf = wfc + a2*62;
            double cv = 0.0;
            #pragma unroll
            for (int k = 0; k < 31; ++k) cv += wf[k]*w0r[k];
            #pragma unroll
            for (int k = 0; k < 31; ++k) cv += wf[31+k]*w1r[k];
            const double e = sb[a2] + cv + pmrow[(size_t)a2*TIN];
            esum += (double)P.v[a2]*tanh(e);
          }
        }
        sb[640 + wv*64 + lane] = esum;
        __syncthreads();
        if (tid < 64){
          const int tg2 = tbase + tid;
          if (tg2 < TIN){
            double e = sb[640+tid] + sb[704+tid] + sb[768+tid] + sb[832+tid];
            if (P.mask[b*TIN + tg2]) e = -1e9;
            st_d(en + b*TIN + tg2, e);
          }
        }
      }
    } else if (wg < 256){
      if (t > 0){
        const int b = wg - 224, ts = t-1;
        for (int i = tid; i < 1536; i += TPB)
          sb[i] = (i < 1024) ? ld_d(dh + b*ARNN + i) : ld_d(ctx + b*EDIM + (i-1024));
        __syncthreads();
        const int o = tid >> 1, hf = tid & 1;
        double s = 0.0;
        if (o <= 80){
          const float* wr = ((o < 80) ? (P.Wp + (size_t)o*1536) : P.Wg) + hf*768;
          const double* xr = sb + hf*768;
          for (int m2 = 0; m2 < 768; ++m2) s += (double)wr[m2]*xr[m2];
        }
        sb[1600 + tid] = s;
        __syncthreads();
        if (tid <= 80){
          double val = sb[1600 + 2*tid] + sb[1600 + 2*tid + 1];
          if (tid < 80) P.out[MEL_OFF + ((size_t)b*NMEL + tid)*TOUT + ts] = (float)(val + (double)P.bp[tid]);
          else          P.out[GATE_OFF + (size_t)b*TOUT + ts] = (float)(val + (double)P.bg[0]);
        }
      }
    }
    gridbar(flags, gen, wg, tid, ++g);

    // ---- PH3: softmax (redundant x8) + ctx slice on ALL 256 WGs ----
    if (t < TOUT){
      const int b = wg >> 3, s = wg & 7;
      // softmax over en[b][0..399] (deterministic -> identical across the 8 s-WGs)
      double m = -1.0e300;
      for (int i = tid; i < TIN; i += TPB){
        double e = ld_d(en + b*TIN + i);
        sb[512 + i] = e;
        m = fmax(m, e);
      }
      sb[tid] = m; __syncthreads();
      for (int s2 = TPB/2; s2 > 0; s2 >>= 1){
        if (tid < s2) sb[tid] = fmax(sb[tid], sb[tid+s2]);
        __syncthreads();
      }
      const double mx = sb[0];
      __syncthreads();
      double ssum = 0.0;
      for (int i = tid; i < TIN; i += TPB){
        double u = exp(sb[512+i] - mx);
        sb[512 + i] = u; ssum += u;
      }
      sb[tid] = ssum; __syncthreads();
      for (int s2 = TPB/2; s2 > 0; s2 >>= 1){
        if (tid < s2) sb[tid] += sb[tid+s2];
        __syncthreads();
      }
      const double tot = sb[0];
      __syncthreads();
      for (int i = tid; i < TIN; i += TPB){
        double a2 = sb[512+i] / tot;
        sb[512+i] = a2;
        if (s == 0){
          st_d(aw + b*TIN + i, a2);
          st_d(awc + b*TIN + i, ld_d(awc + b*TIN + i) + a2);
          P.out[AL_OFF + ((size_t)b*TOUT + t)*TIN + i] = (float)a2;
        }
      }
      __syncthreads();
      // ctx slice: this WG computes e2 in [s*64, s*64+64); t split 4-ways across waves
      {
        const int e2 = s*64 + (tid & 63);
        const int tc = tid >> 6;                     // 0..3 -> t-chunks of 100
        const float* mcol = P.memory + (size_t)b*TIN*EDIM + e2;
        double sacc = 0.0;
        for (int t2 = tc*100; t2 < tc*100 + 100; ++t2)
          sacc += sb[512+t2] * (double)mcol[(size_t)t2*EDIM];
        sb[1024 + tid] = sacc;
        __syncthreads();
        if (tid < 64){
          double v4 = sb[1024+tid] + sb[1088+tid] + sb[1152+tid] + sb[1216+tid];
          st_d(ctx + b*EDIM + s*64 + tid, v4);
        }
      }
    }
    gridbar(flags, gen, wg, tid, ++g);
  }
}

extern "C" void kernel_launch(void* const* d_in, const int* in_sizes, int n_in,
                              void* d_out, int out_size, void* d_ws, size_t ws_size,
                              hipStream_t stream)
{
  const float* memory = (const float*)d_in[0];
  const float* dec    = (const float*)d_in[1];
  const unsigned char* mask = (const unsigned char*)d_in[2];
  const float* W_pre1 = (const float*)d_in[3];
  const float* W_pre2 = (const float*)d_in[4];
  const float* WihA   = (const float*)d_in[5];
  const float* WhhA   = (const float*)d_in[6];
  const float* bihA   = (const float*)d_in[7];
  const float* bhhA   = (const float*)d_in[8];
  const float* Wq     = (const float*)d_in[9];
  const float* Wm     = (const float*)d_in[10];
  const float* v      = (const float*)d_in[11];
  const float* Wc     = (const float*)d_in[12];
  const float* Wd     = (const float*)d_in[13];
  const float* WihD   = (const float*)d_in[14];
  const float* WhhD   = (const float*)d_in[15];
  const float* bihD   = (const float*)d_in[16];
  const float* bhhD   = (const float*)d_in[17];
  const float* Wp     = (const float*)d_in[18];
  const float* bp     = (const float*)d_in[19];
  const float* Wg     = (const float*)d_in[20];
  const float* bg     = (const float*)d_in[21];

  double* ws = (double*)d_ws;
  float* out = (float*)d_out;

  if (ws_size < WS_BYTES){
    sentinel_kernel<<<1, 1, 0, stream>>>(out, 12345.0f);   // diagnostic: ws too small
    return;
  }

  unsigned* bar = (unsigned*)((float*)(ws + DBL_END) + F_END);
  bar_init_kernel<<<1, TPB, 0, stream>>>(bar);
  pm_kernel<<<NB*TIN, TPB, 0, stream>>>(memory, Wm, ws + PM_OFF);
  wfc_kernel<<<1, TPB, 0, stream>>>(Wd, Wc, ws + WFC_OFF);

  DecParams P;
  P.memory = memory; P.dec = dec;
  P.Wpre1 = W_pre1; P.Wpre2 = W_pre2;
  P.WihA = WihA; P.WhhA = WhhA; P.bihA = bihA; P.bhhA = bhhA;
  P.Wq = Wq; P.v = v;
  P.WihD = WihD; P.WhhD = WhhD; P.bihD = bihD; P.bhhD = bhhD;
  P.Wp = Wp; P.bp = bp; P.Wg = Wg; P.bg = bg;
  P.mask = mask; P.ws = ws; P.out = out;

  decoder_main<<<GRID_WGS, TPB, 0, stream>>>(P);
}